// Round 6
// baseline (4680.624 us; speedup 1.0000x reference)
//
#include <hip/hip_runtime.h>
#include <math.h>

constexpr int SVEC = 576;    // N_CH * 64
constexpr int INF  = 2304;   // 4 * SVEC
constexpr int HID  = 256;
constexpr int OUTF = 1152;   // 2 * SVEC
constexpr int TS   = 20;
constexpr int MR   = 16;     // samples per fused1 block
constexpr int CSL  = 24;     // float4-slots per K-chunk (of 144)
constexpr int NCHK = 6;      // 144 / CSL chunks
constexpr int CK   = 96;     // K elems per cc-range per chunk (CSL*4)
constexpr int AROW = 392;    // 4*CK + 8 pad (ushorts) -> stride 196 dw = 4 mod 32

// ---------- helpers ----------------------------------------------------------
__device__ __forceinline__ ushort f2bf(float f) {    // RNE f32->bf16
    union { float f; unsigned u; } a; a.f = f;
    unsigned r = a.u + 0x7fff + ((a.u >> 16) & 1);
    return (ushort)(r >> 16);
}
__device__ __forceinline__ float bf2f(ushort b) {
    union { unsigned u; float f; } a; a.u = ((unsigned)b) << 16;
    return a.f;
}

typedef short  s16x8 __attribute__((ext_vector_type(8)));
typedef float  f32x4 __attribute__((ext_vector_type(4)));

// ---------- init: S = [x|p|y|z] all = [noisy, 0...] --------------------------
__global__ __launch_bounds__(256) void k_init(float4* __restrict__ S4,
                                              const float4* __restrict__ noisy4,
                                              int total4) {
    int i = blockIdx.x * 256 + threadIdx.x;
    if (i >= total4) return;
    int sample = i / 576;
    int j = i - sample * 576;
    int jc = j % 144;
    float4 v = make_float4(0.f, 0.f, 0.f, 0.f);
    if (jc < 16) v = noisy4[sample * 16 + jc];
    S4[i] = v;
}

__global__ __launch_bounds__(128) void k_zero(float* __restrict__ p, int n) {
    int i = blockIdx.x * 128 + threadIdx.x;
    if (i < n) p[i] = 0.f;
}

// ---------- weight transpose + bf16 convert: Wt[n*K+k] = W[k*N+n] ------------
__global__ __launch_bounds__(256) void k_wt(const float* __restrict__ W,
                                            ushort* __restrict__ Wt,
                                            int K, int N, int total) {
    int i = blockIdx.x * 256 + threadIdx.x;
    if (i >= total) return;
    int n = i / K, k = i - n * K;
    Wt[i] = f2bf(W[(size_t)k * N + n]);
}

// ---------- fused FBS + GEMM1, chunked/double-buffered -----------------------
// Per block: 16 samples. K consumed in 6 chunks of 24 slots; FBS of chunk c+1
// overlaps MFMA of chunk c (2 LDS buffers, 18.8 KB each). B-frags direct from
// global/L2 (unpermuted Wt1 [N][K]). Epilogue: bias+ReLU -> bf16 h1.
__global__ __launch_bounds__(256, 4) void k_fused1(float4* __restrict__ S4,
                                                   const ushort4* __restrict__ uvb,
                                                   const float* __restrict__ redprev,
                                                   float* __restrict__ redcur,
                                                   const ushort* __restrict__ Wt1,
                                                   const float* __restrict__ bias,
                                                   ushort* __restrict__ h1,
                                                   float an) {
    __shared__ ushort A[2][MR][AROW];
    __shared__ float s_alpha;
    __shared__ float sr[4], sd[4];
    const int tid = threadIdx.x;
    const int m0 = blockIdx.x * MR;
    const int lane = tid & 63, wave = tid >> 6;
    const int lm = lane & 15, quad = lane >> 4;
    const int wn = wave * 64;

    // ---- alpha from previous step's buckets (slot 0 = zeros -> alpha 0)
    if (tid < 64) {
        float v = (tid < 32) ? redprev[32 + tid] : redprev[64 + (tid - 32)];
        #pragma unroll
        for (int off = 16; off > 0; off >>= 1) v += __shfl_down(v, off);
        float Q = __shfl(v, 32);
        if (tid == 0) {
            float Qs = 1.5f * Q + 1e-12f;
            float b  = 0.99f * fmaxf(v, 0.f);
            s_alpha = sqrtf(fminf(b / Qs, 1.f));
        }
    }
    __syncthreads();
    const float al = s_alpha;

    float r = 0.f, d = 0.f;
    f32x4 acc[4];
    #pragma unroll
    for (int j = 0; j < 4; ++j) acc[j] = (f32x4){0.f, 0.f, 0.f, 0.f};

    // FBS one chunk -> LDS buffer buf
    auto fbs_chunk = [&](int ch, int buf) {
        for (int t = tid; t < MR * CSL; t += 256) {
            int smp = t / CSL, jj = t - smp * CSL;
            int j = ch * CSL + jj;
            size_t base = (size_t)(m0 + smp) * 576 + j;
            float4 x4 = S4[base], p4 = S4[base + 144];
            float4 y4 = S4[base + 288], z4 = S4[base + 432];
            size_t ub = (size_t)(m0 + smp) * 288 + j;
            ushort4 ubv = uvb[ub], vbv = uvb[ub + 144];
            float4 xn4, pr4, yy4, zz4;
            ushort4 bxn, bpr, byy, bzz;
            const float* X = (const float*)&x4;  const float* P = (const float*)&p4;
            const float* Y0 = (const float*)&y4; const float* Z0 = (const float*)&z4;
            const ushort* UB = (const ushort*)&ubv; const ushort* VB = (const ushort*)&vbv;
            float* XN = (float*)&xn4; float* PR = (float*)&pr4;
            float* YY = (float*)&yy4; float* ZZ = (float*)&zz4;
            ushort* BX = (ushort*)&bxn; ushort* BP = (ushort*)&bpr;
            ushort* BY = (ushort*)&byy; ushort* BZ = (ushort*)&bzz;
            #pragma unroll
            for (int c = 0; c < 4; ++c) {
                float x = X[c], p = P[c], y0 = Y0[c], z0 = Z0[c];
                float u = al * bf2f(UB[c]), v = al * bf2f(VB[c]);
                float y  = x + an * (y0 - x) + u;
                float dz = an * (z0 - p);
                float z  = x + an * (p - x) + dz + u + v;
                float zm = z - y;
                float tt = fabsf(zm) - 0.1f;
                float pr = (tt > 0.f) ? copysignf(tt, zm) : 0.f;
                float xn = x + (pr - z) + dz;
                XN[c] = xn; PR[c] = pr; YY[c] = y; ZZ[c] = z;
                BX[c] = f2bf(xn); BP[c] = f2bf(pr); BY[c] = f2bf(y); BZ[c] = f2bf(z);
                float e1 = pr - y; r += e1 * e1;
                float e2 = xn - z; d += e2 * e2;
            }
            S4[base] = xn4; S4[base + 144] = pr4;
            S4[base + 288] = yy4; S4[base + 432] = zz4;
            ushort* Ar = &A[buf][smp][0];
            *(ushort4*)&Ar[         jj * 4] = bxn;
            *(ushort4*)&Ar[CK     + jj * 4] = bpr;
            *(ushort4*)&Ar[2 * CK + jj * 4] = byy;
            *(ushort4*)&Ar[3 * CK + jj * 4] = bzz;
        }
    };
    // MFMA one chunk from LDS buffer buf (K ranges cc*576 + ch*CK .. +CK)
    auto mfma_chunk = [&](int ch, int buf) {
        #pragma unroll
        for (int cc = 0; cc < 4; ++cc) {
            const ushort* Wb = Wt1 + (size_t)(wn + lm) * INF + cc * 576 + ch * CK;
            #pragma unroll
            for (int k0 = 0; k0 < CK; k0 += 32) {
                s16x8 af  = *(const s16x8*)&A[buf][lm][cc * CK + k0 + quad * 8];
                s16x8 bf0 = *(const s16x8*)(Wb + (size_t) 0 * INF + k0 + quad * 8);
                s16x8 bf1 = *(const s16x8*)(Wb + (size_t)16 * INF + k0 + quad * 8);
                s16x8 bf2 = *(const s16x8*)(Wb + (size_t)32 * INF + k0 + quad * 8);
                s16x8 bf3 = *(const s16x8*)(Wb + (size_t)48 * INF + k0 + quad * 8);
                acc[0] = __builtin_amdgcn_mfma_f32_16x16x32_bf16(af, bf0, acc[0], 0, 0, 0);
                acc[1] = __builtin_amdgcn_mfma_f32_16x16x32_bf16(af, bf1, acc[1], 0, 0, 0);
                acc[2] = __builtin_amdgcn_mfma_f32_16x16x32_bf16(af, bf2, acc[2], 0, 0, 0);
                acc[3] = __builtin_amdgcn_mfma_f32_16x16x32_bf16(af, bf3, acc[3], 0, 0, 0);
            }
        }
    };

    fbs_chunk(0, 0);
    __syncthreads();
    #pragma unroll
    for (int ch = 0; ch < NCHK; ++ch) {
        if (ch + 1 < NCHK) fbs_chunk(ch + 1, (ch + 1) & 1);
        mfma_chunk(ch, ch & 1);
        __syncthreads();
    }

    // ---- r/d reduction -> bucketized atomics
    #pragma unroll
    for (int off = 32; off > 0; off >>= 1) {
        r += __shfl_down(r, off);
        d += __shfl_down(d, off);
    }
    if (lane == 0) { sr[wave] = r; sd[wave] = d; }
    __syncthreads();
    if (tid == 0) {
        int bk = blockIdx.x & 31;
        atomicAdd(&redcur[bk],      sr[0] + sr[1] + sr[2] + sr[3]);
        atomicAdd(&redcur[32 + bk], sd[0] + sd[1] + sd[2] + sd[3]);
    }

    // ---- epilogue: bias + ReLU -> bf16 h1 (16 x 256)
    #pragma unroll
    for (int j = 0; j < 4; ++j) {
        int col = wn + j * 16 + lm;
        float bb = bias[col];
        #pragma unroll
        for (int rr = 0; rr < 4; ++rr) {
            int row = m0 + quad * 4 + rr;
            float c = fmaxf(acc[j][rr] + bb, 0.f);
            h1[(size_t)row * HID + col] = f2bf(c);
        }
    }
}

// ---------- fused GEMM2 + GEMM3: h1 -> (relu) h2(LDS) -> uv + Q --------------
// 32-row blocks; Wt2/Wt3 B-frags direct from global/L2; uv bf16 out.
__global__ __launch_bounds__(256, 4) void k_fused23(const ushort* __restrict__ h1,
                                                    const ushort* __restrict__ Wt2,
                                                    const float* __restrict__ b2,
                                                    const ushort* __restrict__ Wt3,
                                                    const float* __restrict__ b3,
                                                    ushort* __restrict__ uv,
                                                    float* __restrict__ redcur) {
    __shared__ ushort H1[32][264];
    __shared__ ushort H2[32][264];
    const int tid = threadIdx.x;
    const int m0 = blockIdx.x * 32;
    const int lane = tid & 63, wave = tid >> 6;
    const int lm = lane & 15, quad = lane >> 4;

    // stage h1 tile (32 x 256 bf16) via 16B loads
    #pragma unroll
    for (int i = 0; i < 4; ++i) {
        int idx = tid + i * 256;             // 0..1023
        int row = idx >> 5, c8 = idx & 31;
        s16x8 v = *(const s16x8*)&h1[(size_t)(m0 + row) * HID + c8 * 8];
        *(s16x8*)&H1[row][c8 * 8] = v;
    }
    __syncthreads();

    // ---- GEMM2: 32 x 256, K=256; wave covers 64 cols
    const int wn = wave * 64;
    f32x4 a2[2][4];
    #pragma unroll
    for (int i = 0; i < 2; ++i)
        #pragma unroll
        for (int j = 0; j < 4; ++j) a2[i][j] = (f32x4){0.f, 0.f, 0.f, 0.f};
    const ushort* W2b = Wt2 + (size_t)(wn + lm) * HID;
    #pragma unroll
    for (int k0 = 0; k0 < HID; k0 += 32) {
        s16x8 af0 = *(const s16x8*)&H1[lm][k0 + quad * 8];
        s16x8 af1 = *(const s16x8*)&H1[16 + lm][k0 + quad * 8];
        #pragma unroll
        for (int j = 0; j < 4; ++j) {
            s16x8 bf = *(const s16x8*)(W2b + (size_t)j * 16 * HID + k0 + quad * 8);
            a2[0][j] = __builtin_amdgcn_mfma_f32_16x16x32_bf16(af0, bf, a2[0][j], 0, 0, 0);
            a2[1][j] = __builtin_amdgcn_mfma_f32_16x16x32_bf16(af1, bf, a2[1][j], 0, 0, 0);
        }
    }
    #pragma unroll
    for (int j = 0; j < 4; ++j) {
        int col = wn + j * 16 + lm;
        float bb = b2[col];
        #pragma unroll
        for (int i = 0; i < 2; ++i)
            #pragma unroll
            for (int rr = 0; rr < 4; ++rr) {
                int row = i * 16 + quad * 4 + rr;
                H2[row][col] = f2bf(fmaxf(a2[i][j][rr] + bb, 0.f));
            }
    }
    __syncthreads();

    // ---- GEMM3: 32 x 1152, K=256; 3 passes of 384 cols (wave: 96 cols/pass)
    float q = 0.f;
    #pragma unroll
    for (int pp = 0; pp < 3; ++pp) {
        f32x4 a3[2][6];
        #pragma unroll
        for (int i = 0; i < 2; ++i)
            #pragma unroll
            for (int j = 0; j < 6; ++j) a3[i][j] = (f32x4){0.f, 0.f, 0.f, 0.f};
        const int cb = pp * 384 + wave * 96;
        const ushort* W3b = Wt3 + (size_t)(cb + lm) * HID;
        #pragma unroll
        for (int k0 = 0; k0 < HID; k0 += 32) {
            s16x8 af0 = *(const s16x8*)&H2[lm][k0 + quad * 8];
            s16x8 af1 = *(const s16x8*)&H2[16 + lm][k0 + quad * 8];
            #pragma unroll
            for (int j = 0; j < 6; ++j) {
                s16x8 bf = *(const s16x8*)(W3b + (size_t)j * 16 * HID + k0 + quad * 8);
                a3[0][j] = __builtin_amdgcn_mfma_f32_16x16x32_bf16(af0, bf, a3[0][j], 0, 0, 0);
                a3[1][j] = __builtin_amdgcn_mfma_f32_16x16x32_bf16(af1, bf, a3[1][j], 0, 0, 0);
            }
        }
        #pragma unroll
        for (int j = 0; j < 6; ++j) {
            int col = cb + j * 16 + lm;
            float bb = b3[col];
            #pragma unroll
            for (int i = 0; i < 2; ++i)
                #pragma unroll
                for (int rr = 0; rr < 4; ++rr) {
                    int row = i * 16 + quad * 4 + rr;
                    float c = a3[i][j][rr] + bb;
                    q += c * c;
                    uv[(size_t)(m0 + row) * OUTF + col] = f2bf(c);
                }
        }
    }
    #pragma unroll
    for (int off = 32; off > 0; off >>= 1) q += __shfl_down(q, off);
    __shared__ float sq[4];
    if (lane == 0) sq[wave] = q;
    __syncthreads();
    if (tid == 0)
        atomicAdd(&redcur[64 + (blockIdx.x & 31)], sq[0] + sq[1] + sq[2] + sq[3]);
}

// ---------- finish: p_final = S chunk 1; block 0 folds residuals -------------
__global__ __launch_bounds__(256) void k_finish(const float4* __restrict__ S4,
                                                float4* __restrict__ out4,
                                                const float* __restrict__ red,
                                                float* __restrict__ res_out,
                                                int total4) {
    int i = blockIdx.x * 256 + threadIdx.x;
    if (blockIdx.x == 0 && threadIdx.x < TS) {
        const float* rb = red + (threadIdx.x + 1) * 96;
        float s = 0.f;
        #pragma unroll
        for (int c = 0; c < 32; ++c) s += rb[c];
        res_out[threadIdx.x] = sqrtf(s + 1e-12f);
    }
    if (i >= total4) return;
    int sample = i / 144;
    int j = i - sample * 144;
    out4[i] = S4[(size_t)sample * 576 + 144 + j];
}

extern "C" void kernel_launch(void* const* d_in, const int* in_sizes, int n_in,
                              void* d_out, int out_size, void* d_ws, size_t ws_size,
                              hipStream_t stream) {
    const float* noisy = (const float*)d_in[0];
    const float* W1 = (const float*)d_in[1];
    const float* b1 = (const float*)d_in[2];
    const float* W2 = (const float*)d_in[3];
    const float* b2 = (const float*)d_in[4];
    const float* W3 = (const float*)d_in[5];
    const float* b3 = (const float*)d_in[6];
    const int B = in_sizes[0] / 64;   // 16384

    // workspace layout (~208 MB)
    float*  S   = (float*)d_ws;                         // [B,2304] f32
    ushort* h1  = (ushort*)(S + (size_t)B * INF);       // [B,256]  bf16
    ushort* h2x = h1 + (size_t)B * HID;                 // (spare)
    ushort* Wt1 = h2x + (size_t)B * HID;                // [256,2304] bf16
    ushort* Wt2 = Wt1 + (size_t)HID * INF;              // [256,256]  bf16
    ushort* Wt3 = Wt2 + (size_t)HID * HID;              // [1152,256] bf16
    float*  red = (float*)(Wt3 + (size_t)OUTF * HID);   // 21 slots x 96
    ushort* uv  = (ushort*)(red + 21 * 96);             // [B,1152] bf16

    float* p_out   = (float*)d_out;                     // [B,576]
    float* res_out = p_out + (size_t)B * SVEC;          // [20]

    const int tot4 = B * 144;

    k_init<<<(tot4 * 4 + 255) / 256, 256, 0, stream>>>((float4*)S, (const float4*)noisy, tot4 * 4);
    k_zero<<<(21 * 96 + 127) / 128, 128, 0, stream>>>(red, 21 * 96);
    k_zero<<<((B * OUTF / 2) + 127) / 128, 128, 0, stream>>>((float*)uv, B * OUTF / 2);
    k_wt<<<(HID * INF + 255) / 256, 256, 0, stream>>>(W1, Wt1, INF, HID, HID * INF);
    k_wt<<<(HID * HID + 255) / 256, 256, 0, stream>>>(W2, Wt2, HID, HID, HID * HID);
    k_wt<<<(OUTF * HID + 255) / 256, 256, 0, stream>>>(W3, Wt3, HID, OUTF, OUTF * HID);

    const int gf  = B / MR;      // 1024 fused1 blocks
    const int g23 = B / 32;      // 512 fused23 blocks

    for (int n = 0; n < TS; ++n) {
        float an = (float)n / ((float)n + 3.0f);
        float* redprev = red + (size_t)n * 96;
        float* redcur  = red + (size_t)(n + 1) * 96;
        k_fused1<<<gf, 256, 0, stream>>>((float4*)S, (const ushort4*)uv,
                                         redprev, redcur, Wt1, b1, h1, an);
        k_fused23<<<g23, 256, 0, stream>>>(h1, Wt2, b2, Wt3, b3, uv, redcur);
    }
    k_finish<<<(tot4 + 255) / 256, 256, 0, stream>>>((const float4*)S, (float4*)p_out,
                                                     red, res_out, tot4);
}